// Round 1
// baseline (379.008 us; speedup 1.0000x reference)
//
#include <hip/hip_runtime.h>

typedef unsigned short u16;
typedef unsigned int u32;
typedef __bf16 bf16x8 __attribute__((ext_vector_type(8)));
typedef float f32x4 __attribute__((ext_vector_type(4)));

__device__ __forceinline__ u16 f2bf(float f) {
  u32 u = __float_as_uint(f);
  u32 r = (u + 0x7FFFu + ((u >> 16) & 1u)) >> 16;
  return (u16)r;
}

__device__ __forceinline__ float gelu_exact(float x) {
  return 0.5f * x * (1.f + erff(x * 0.70710678118654752f));
}

// ---------------- transpose + cast fp32 [R,C] -> bf16 [C,R] ----------------
__global__ void transpose_cast(const float* __restrict__ in, u16* __restrict__ out,
                               int R, int C) {
  __shared__ float tile[32][33];
  int c0 = blockIdx.x * 32, r0 = blockIdx.y * 32;
  int tx = threadIdx.x, ty = threadIdx.y;  // 32 x 8
  for (int i = 0; i < 32; i += 8) {
    int r = r0 + ty + i, c = c0 + tx;
    tile[ty + i][tx] = (r < R && c < C) ? in[(long)r * C + c] : 0.f;
  }
  __syncthreads();
  for (int i = 0; i < 32; i += 8) {
    int oc = c0 + ty + i, orr = r0 + tx;
    if (oc < C && orr < R) out[(long)oc * R + orr] = f2bf(tile[tx][ty + i]);
  }
}

// ------- W_eff^T[n,d] = sum_j lin_w[j*64+d, n]  (tile-of-12 folded GEMM) -------
__global__ void weff_build(const float* __restrict__ lin_w, u16* __restrict__ weffT) {
  int idx = blockIdx.x * 256 + threadIdx.x;
  if (idx >= 768 * 64) return;
  int n = idx % 768, d = idx / 768;
  float s = 0.f;
#pragma unroll
  for (int j = 0; j < 12; j++) s += lin_w[(long)(j * 64 + d) * 768 + n];
  weffT[(long)n * 64 + d] = f2bf(s);
}

// ---------------- LayerNorm: one wave per 768-row, bf16 out ----------------
__global__ __launch_bounds__(256)
void ln_rows(const float* __restrict__ in, const float* __restrict__ gamma,
             const float* __restrict__ beta, u16* __restrict__ out, int nrows) {
  int gid = blockIdx.x * blockDim.x + threadIdx.x;
  int wid = gid >> 6, l = gid & 63;
  if (wid >= nrows) return;
  const float4* row = (const float4*)(in + (long)wid * 768);
  float4 v[3];
  float s = 0.f, s2 = 0.f;
#pragma unroll
  for (int j = 0; j < 3; j++) {
    v[j] = row[l + 64 * j];
    s += v[j].x + v[j].y + v[j].z + v[j].w;
    s2 += v[j].x * v[j].x + v[j].y * v[j].y + v[j].z * v[j].z + v[j].w * v[j].w;
  }
#pragma unroll
  for (int off = 1; off < 64; off <<= 1) {
    s += __shfl_xor(s, off);
    s2 += __shfl_xor(s2, off);
  }
  float mean = s * (1.f / 768.f);
  float rstd = rsqrtf(s2 * (1.f / 768.f) - mean * mean + 1e-5f);
  u16* orow = out + (long)wid * 768;
#pragma unroll
  for (int j = 0; j < 3; j++) {
    float4 g = ((const float4*)gamma)[l + 64 * j];
    float4 b = ((const float4*)beta)[l + 64 * j];
    ushort4 o;
    o.x = f2bf((v[j].x - mean) * rstd * g.x + b.x);
    o.y = f2bf((v[j].y - mean) * rstd * g.y + b.y);
    o.z = f2bf((v[j].z - mean) * rstd * g.z + b.z);
    o.w = f2bf((v[j].w - mean) * rstd * g.w + b.w);
    ((ushort4*)orow)[l + 64 * j] = o;
  }
}

// ---------------- generic bf16 GEMM, Bt is [Npad,K] (B^T), 128x128 tile ----------------
// EPI 0: bf16 out, no bias.  EPI 1: f32 out = acc + bias + res.  EPI 2: bf16 out = gelu(acc+bias).
template <int EPI>
__global__ __launch_bounds__(256, 2)
void gemm_bt(const u16* __restrict__ A, const u16* __restrict__ Bt,
             const float* __restrict__ bias, const float* __restrict__ res,
             void* __restrict__ outv, int M, int N, int K, int ldo) {
  __shared__ __align__(16) u16 Alds[128 * 40];  // row stride 40 elems (padded, 80B)
  __shared__ __align__(16) u16 Blds[128 * 40];
  const int t = threadIdx.x;
  const int w = t >> 6, l = t & 63;
  const int wr = w >> 1, wc = w & 1;
  const u16* aptr = A + ((long)(blockIdx.x * 128 + (t >> 2))) * K + (t & 3) * 8;
  const u16* bptr = Bt + ((long)(blockIdx.y * 128 + (t >> 2))) * K + (t & 3) * 8;
  const long step64 = (long)64 * K;
  const int lw0 = (t >> 2) * 40 + (t & 3) * 8;
  const int lw1 = lw0 + 64 * 40;
  const int ar = (wr * 64 + (l & 15)) * 40 + ((l >> 4) * 8);
  const int br = (wc * 64 + (l & 15)) * 40 + ((l >> 4) * 8);
  f32x4 acc[4][4] = {};
  const int ksteps = K >> 5;
  for (int ks = 0; ks < ksteps; ++ks) {
    uint4 a0 = *(const uint4*)(aptr);
    uint4 a1 = *(const uint4*)(aptr + step64);
    uint4 b0 = *(const uint4*)(bptr);
    uint4 b1 = *(const uint4*)(bptr + step64);
    __syncthreads();
    *(uint4*)(&Alds[lw0]) = a0;
    *(uint4*)(&Alds[lw1]) = a1;
    *(uint4*)(&Blds[lw0]) = b0;
    *(uint4*)(&Blds[lw1]) = b1;
    __syncthreads();
    bf16x8 af[4], bfr[4];
#pragma unroll
    for (int i = 0; i < 4; i++) af[i] = *(const bf16x8*)(&Alds[ar + i * 16 * 40]);
#pragma unroll
    for (int i = 0; i < 4; i++) bfr[i] = *(const bf16x8*)(&Blds[br + i * 16 * 40]);
#pragma unroll
    for (int mf = 0; mf < 4; mf++)
#pragma unroll
      for (int nf = 0; nf < 4; nf++)
        acc[mf][nf] = __builtin_amdgcn_mfma_f32_16x16x32_bf16(af[mf], bfr[nf], acc[mf][nf], 0, 0, 0);
    aptr += 32;
    bptr += 32;
  }
  const int rowbase = blockIdx.x * 128 + wr * 64 + ((l >> 4) * 4);
  const int colbase = blockIdx.y * 128 + wc * 64 + (l & 15);
#pragma unroll
  for (int nf = 0; nf < 4; nf++) {
    int col = colbase + nf * 16;
    if (col >= N) continue;
    float bv = (EPI == 0) ? 0.f : bias[col];
#pragma unroll
    for (int mf = 0; mf < 4; mf++) {
#pragma unroll
      for (int i = 0; i < 4; i++) {
        long row = rowbase + mf * 16 + i;
        float v = acc[mf][nf][i] + bv;
        if (EPI == 2) v = gelu_exact(v);
        if (EPI == 1) {
          v += res[row * ldo + col];
          ((float*)outv)[row * ldo + col] = v;
        } else {
          ((u16*)outv)[row * ldo + col] = f2bf(v);
        }
      }
    }
  }
}

// ---------------- flash attention: qkv [8192,192] bf16 -> oh [8192,64] bf16 ----------------
// blocks of 128 threads (2 waves); each wave owns 16 Q-rows; KV tiles of 32.
__global__ __launch_bounds__(128)
void attn_fwd(const u16* __restrict__ qkv, u16* __restrict__ oh) {
  __shared__ __align__(16) u16 Klds[32 * 72];      // [key][feat] padded 64->72
  __shared__ __align__(16) u16 Vlds[64 * 40];      // [feat][key] padded 32->40
  __shared__ __align__(16) u16 Plds[2][16 * 40];   // per-wave P tile [qrow][key]
  const int t = threadIdx.x, w = t >> 6, l = t & 63;
  const int r0 = blockIdx.x * 32;
  const long bb = (long)(r0 & ~2047);  // batch row base
  const int qrow = r0 + w * 16 + (l & 15);
  bf16x8 qf0 = *(const bf16x8*)(qkv + (long)qrow * 192 + ((l >> 4) * 8));
  bf16x8 qf1 = *(const bf16x8*)(qkv + (long)qrow * 192 + 32 + ((l >> 4) * 8));
  f32x4 po[4] = {};
  float m_i[4], l_i[4];
#pragma unroll
  for (int i = 0; i < 4; i++) { m_i[i] = -1e30f; l_i[i] = 0.f; }
  const int kkey = t >> 3, kseg = t & 7;
  for (int st = 0; st < 2048; st += 32) {
    uint4 k0 = *(const uint4*)(qkv + (bb + st + kkey) * 192 + 64 + kseg * 8);
    uint4 k1 = *(const uint4*)(qkv + (bb + st + 16 + kkey) * 192 + 64 + kseg * 8);
    u16 vv[16];
#pragma unroll
    for (int i = 0; i < 16; i++) {
      int e = t + 128 * i;
      vv[i] = qkv[(bb + st + (e >> 6)) * 192 + 128 + (e & 63)];
    }
    __syncthreads();  // prior iter's LDS reads done
    *(uint4*)(&Klds[kkey * 72 + kseg * 8]) = k0;
    *(uint4*)(&Klds[(16 + kkey) * 72 + kseg * 8]) = k1;
#pragma unroll
    for (int i = 0; i < 16; i++) {
      int e = t + 128 * i;
      Vlds[(e & 63) * 40 + (e >> 6)] = vv[i];  // transposed store
    }
    __syncthreads();
    // S = (Q @ K^T) * 0.125, two 16-key halves
    f32x4 s0 = {}, s1 = {};
    {
      bf16x8 ka = *(const bf16x8*)(&Klds[(l & 15) * 72 + ((l >> 4) * 8)]);
      bf16x8 kb = *(const bf16x8*)(&Klds[(l & 15) * 72 + 32 + ((l >> 4) * 8)]);
      s0 = __builtin_amdgcn_mfma_f32_16x16x32_bf16(qf0, ka, s0, 0, 0, 0);
      s0 = __builtin_amdgcn_mfma_f32_16x16x32_bf16(qf1, kb, s0, 0, 0, 0);
      bf16x8 kc = *(const bf16x8*)(&Klds[(16 + (l & 15)) * 72 + ((l >> 4) * 8)]);
      bf16x8 kd = *(const bf16x8*)(&Klds[(16 + (l & 15)) * 72 + 32 + ((l >> 4) * 8)]);
      s1 = __builtin_amdgcn_mfma_f32_16x16x32_bf16(qf0, kc, s1, 0, 0, 0);
      s1 = __builtin_amdgcn_mfma_f32_16x16x32_bf16(qf1, kd, s1, 0, 0, 0);
    }
    float sf[4];
#pragma unroll
    for (int i = 0; i < 4; i++) {
      float a = s0[i] * 0.125f, b = s1[i] * 0.125f;
      float tm = fmaxf(a, b);
#pragma unroll
      for (int off = 1; off < 16; off <<= 1) tm = fmaxf(tm, __shfl_xor(tm, off));
      float mn = fmaxf(m_i[i], tm);
      sf[i] = __expf(m_i[i] - mn);
      m_i[i] = mn;
      a = __expf(a - mn);
      b = __expf(b - mn);
      float rs = a + b;
#pragma unroll
      for (int off = 1; off < 16; off <<= 1) rs += __shfl_xor(rs, off);
      l_i[i] = l_i[i] * sf[i] + rs;
      int prow = (l >> 4) * 4 + i;
      Plds[w][prow * 40 + (l & 15)] = f2bf(a);
      Plds[w][prow * 40 + 16 + (l & 15)] = f2bf(b);
    }
#pragma unroll
    for (int n = 0; n < 4; n++)
#pragma unroll
      for (int i = 0; i < 4; i++) po[n][i] *= sf[i];
    // PV
    bf16x8 pf = *(const bf16x8*)(&Plds[w][(l & 15) * 40 + ((l >> 4) * 8)]);
#pragma unroll
    for (int n = 0; n < 4; n++) {
      bf16x8 vf = *(const bf16x8*)(&Vlds[(n * 16 + (l & 15)) * 40 + ((l >> 4) * 8)]);
      po[n] = __builtin_amdgcn_mfma_f32_16x16x32_bf16(pf, vf, po[n], 0, 0, 0);
    }
  }
#pragma unroll
  for (int n = 0; n < 4; n++)
#pragma unroll
    for (int i = 0; i < 4; i++) {
      long row = r0 + w * 16 + ((l >> 4) * 4) + i;
      int feat = n * 16 + (l & 15);
      oh[row * 64 + feat] = f2bf(po[n][i] / l_i[i]);
    }
}

extern "C" void kernel_launch(void* const* d_in, const int* in_sizes, int n_in,
                              void* d_out, int out_size, void* d_ws, size_t ws_size,
                              hipStream_t stream) {
  const float* x = (const float*)d_in[0];
  const float* wq = (const float*)d_in[1];
  const float* wk = (const float*)d_in[2];
  const float* wv = (const float*)d_in[3];
  const float* lin_w = (const float*)d_in[4];
  const float* lin_b = (const float*)d_in[5];
  const float* ln1_g = (const float*)d_in[6];
  const float* ln1_b = (const float*)d_in[7];
  const float* fc1_w = (const float*)d_in[8];
  const float* fc1_b = (const float*)d_in[9];
  const float* fc2_w = (const float*)d_in[10];
  const float* fc2_b = (const float*)d_in[11];
  float* out = (float*)d_out;

  char* p = (char*)d_ws;
  u16* wqkvT = (u16*)p; p += 256 * 768 * 2;          // [256(pad from 192), 768]
  u16* weffT = (u16*)p; p += 768 * 64 * 2;           // [768, 64]
  u16* fc1wT = (u16*)p; p += (size_t)3072 * 768 * 2; // [3072, 768]
  u16* fc2wT = (u16*)p; p += (size_t)768 * 3072 * 2; // [768, 3072]
  u16* h = (u16*)p; p += (size_t)8192 * 768 * 2;     // LN out (reused for LN2 out)
  u16* qkv = (u16*)p; p += (size_t)8192 * 192 * 2;   // [rows, q|k|v]
  u16* oh = (u16*)p; p += (size_t)8192 * 64 * 2;     // attention head out
  float* out1 = (float*)p; p += (size_t)8192 * 768 * 4;  // residual-1 output
  u16* a1 = (u16*)p; p += (size_t)8192 * 3072 * 2;   // gelu(fc1) out

  dim3 tb(32, 8);
  // weight prep (bf16, transposed [N,K])
  transpose_cast<<<dim3(2, 24), tb, 0, stream>>>(wq, wqkvT, 768, 64);
  transpose_cast<<<dim3(2, 24), tb, 0, stream>>>(wk, wqkvT + 64 * 768, 768, 64);
  transpose_cast<<<dim3(2, 24), tb, 0, stream>>>(wv, wqkvT + 128 * 768, 768, 64);
  hipMemsetAsync(wqkvT + 192 * 768, 0, 64 * 768 * 2, stream);  // pad rows 192..255
  transpose_cast<<<dim3(96, 24), tb, 0, stream>>>(fc1_w, fc1wT, 768, 3072);
  transpose_cast<<<dim3(24, 96), tb, 0, stream>>>(fc2_w, fc2wT, 3072, 768);
  weff_build<<<192, 256, 0, stream>>>(lin_w, weffT);

  // pipeline
  ln_rows<<<2048, 256, 0, stream>>>(x, ln1_g, ln1_b, h, 8192);
  gemm_bt<0><<<dim3(64, 2), 256, 0, stream>>>(h, wqkvT, nullptr, nullptr, qkv,
                                              8192, 192, 768, 192);
  attn_fwd<<<256, 128, 0, stream>>>(qkv, oh);
  gemm_bt<1><<<dim3(64, 6), 256, 0, stream>>>(oh, weffT, lin_b, x, out1,
                                              8192, 768, 64, 768);
  ln_rows<<<2048, 256, 0, stream>>>(out1, ln1_g, ln1_b, h, 8192);
  gemm_bt<2><<<dim3(64, 24), 256, 0, stream>>>(h, fc1wT, fc1_b, nullptr, a1,
                                               8192, 3072, 768, 3072);
  gemm_bt<1><<<dim3(64, 6), 256, 0, stream>>>(a1, fc2wT, fc2_b, out1, out,
                                              8192, 768, 3072, 768);
}

// Round 2
// 332.753 us; speedup vs baseline: 1.1390x; 1.1390x over previous
//
#include <hip/hip_runtime.h>

typedef unsigned short u16;
typedef unsigned int u32;
typedef __bf16 bf16x8 __attribute__((ext_vector_type(8)));
typedef float f32x4 __attribute__((ext_vector_type(4)));

__device__ __forceinline__ u16 f2bf(float f) {
  u32 u = __float_as_uint(f);
  u32 r = (u + 0x7FFFu + ((u >> 16) & 1u)) >> 16;
  return (u16)r;
}

__device__ __forceinline__ float gelu_exact(float x) {
  return 0.5f * x * (1.f + erff(x * 0.70710678118654752f));
}

// async global->LDS, 16B per lane. LDS dest is wave-uniform base + lane*16.
__device__ __forceinline__ void gload16(const u16* g, u16* l) {
  __builtin_amdgcn_global_load_lds((const __attribute__((address_space(1))) void*)g,
                                   (__attribute__((address_space(3))) void*)l, 16, 0, 0);
}

// ---------------- transpose + cast fp32 [R,C] -> bf16 [C,R] ----------------
__global__ void transpose_cast(const float* __restrict__ in, u16* __restrict__ out,
                               int R, int C) {
  __shared__ float tile[32][33];
  int c0 = blockIdx.x * 32, r0 = blockIdx.y * 32;
  int tx = threadIdx.x, ty = threadIdx.y;  // 32 x 8
  for (int i = 0; i < 32; i += 8) {
    int r = r0 + ty + i, c = c0 + tx;
    tile[ty + i][tx] = (r < R && c < C) ? in[(long)r * C + c] : 0.f;
  }
  __syncthreads();
  for (int i = 0; i < 32; i += 8) {
    int oc = c0 + ty + i, orr = r0 + tx;
    if (oc < C && orr < R) out[(long)oc * R + orr] = f2bf(tile[tx][ty + i]);
  }
}

// ------- W_eff^T[n,d] = sum_j lin_w[j*64+d, n]  (tile-of-12 folded GEMM) -------
__global__ void weff_build(const float* __restrict__ lin_w, u16* __restrict__ weffT) {
  int idx = blockIdx.x * 256 + threadIdx.x;
  if (idx >= 768 * 64) return;
  int n = idx % 768, d = idx / 768;
  float s = 0.f;
#pragma unroll
  for (int j = 0; j < 12; j++) s += lin_w[(long)(j * 64 + d) * 768 + n];
  weffT[(long)n * 64 + d] = f2bf(s);
}

// ---------------- LayerNorm: one wave per 768-row, bf16 out ----------------
__global__ __launch_bounds__(256)
void ln_rows(const float* __restrict__ in, const float* __restrict__ gamma,
             const float* __restrict__ beta, u16* __restrict__ out, int nrows) {
  int gid = blockIdx.x * blockDim.x + threadIdx.x;
  int wid = gid >> 6, l = gid & 63;
  if (wid >= nrows) return;
  const float4* row = (const float4*)(in + (long)wid * 768);
  float4 v[3];
  float s = 0.f, s2 = 0.f;
#pragma unroll
  for (int j = 0; j < 3; j++) {
    v[j] = row[l + 64 * j];
    s += v[j].x + v[j].y + v[j].z + v[j].w;
    s2 += v[j].x * v[j].x + v[j].y * v[j].y + v[j].z * v[j].z + v[j].w * v[j].w;
  }
#pragma unroll
  for (int off = 1; off < 64; off <<= 1) {
    s += __shfl_xor(s, off);
    s2 += __shfl_xor(s2, off);
  }
  float mean = s * (1.f / 768.f);
  float rstd = rsqrtf(s2 * (1.f / 768.f) - mean * mean + 1e-5f);
  u16* orow = out + (long)wid * 768;
#pragma unroll
  for (int j = 0; j < 3; j++) {
    float4 g = ((const float4*)gamma)[l + 64 * j];
    float4 b = ((const float4*)beta)[l + 64 * j];
    ushort4 o;
    o.x = f2bf((v[j].x - mean) * rstd * g.x + b.x);
    o.y = f2bf((v[j].y - mean) * rstd * g.y + b.y);
    o.z = f2bf((v[j].z - mean) * rstd * g.z + b.z);
    o.w = f2bf((v[j].w - mean) * rstd * g.w + b.w);
    ((ushort4*)orow)[l + 64 * j] = o;
  }
}

// ------------- generic bf16 GEMM, Bt is [Npad,K] (B^T), 128x128 tile, BK=32 -------------
// m97 structure: global_load_lds width-16 staging into LINEAR LDS [128][32].
// EPI 0: bf16 out, no bias.  EPI 1: f32 out = acc + bias + res.  EPI 2: bf16 out = gelu(acc+bias).
template <int EPI>
__global__ __launch_bounds__(256, 2)
void gemm_bt(const u16* __restrict__ A, const u16* __restrict__ Bt,
             const float* __restrict__ bias, const float* __restrict__ res,
             void* __restrict__ outv, int M, int N, int K, int ldo) {
  __shared__ __align__(16) u16 Alds[128 * 32];
  __shared__ __align__(16) u16 Blds[128 * 32];
  const int t = threadIdx.x;
  const int w = t >> 6, l = t & 63;
  const int wr = w >> 1, wc = w & 1;
  // staging: wave w covers rows [w*32, w*32+32) in two 16-row issues.
  // lane l -> row w*32 + (l>>2) (+16 for issue 2), col element (l&3)*8.
  const int srow = w * 32 + (l >> 2);
  const int scol = (l & 3) * 8;
  const u16* aptr = A + (long)(blockIdx.x * 128 + srow) * K + scol;
  const u16* bptr = Bt + (long)(blockIdx.y * 128 + srow) * K + scol;
  const long j16 = (long)16 * K;  // 16-row stride (elements)
  u16* albase = &Alds[(w * 32) * 32];  // wave-uniform LDS dest
  u16* blbase = &Blds[(w * 32) * 32];
  const int ar = (wr * 64 + (l & 15)) * 32 + (l >> 4) * 8;
  const int br = (wc * 64 + (l & 15)) * 32 + (l >> 4) * 8;
  f32x4 acc[4][4] = {};
  for (int ks = 0; ks < K; ks += 32) {
    __syncthreads();  // prior iter's LDS reads done before overwrite
    gload16(aptr, albase);
    gload16(aptr + j16, albase + 16 * 32);
    gload16(bptr, blbase);
    gload16(bptr + j16, blbase + 16 * 32);
    asm volatile("s_waitcnt vmcnt(0)" ::: "memory");
    __syncthreads();
    bf16x8 af[4], bfr[4];
#pragma unroll
    for (int i = 0; i < 4; i++) af[i] = *(const bf16x8*)(&Alds[ar + i * 16 * 32]);
#pragma unroll
    for (int i = 0; i < 4; i++) bfr[i] = *(const bf16x8*)(&Blds[br + i * 16 * 32]);
#pragma unroll
    for (int mf = 0; mf < 4; mf++)
#pragma unroll
      for (int nf = 0; nf < 4; nf++)
        acc[mf][nf] = __builtin_amdgcn_mfma_f32_16x16x32_bf16(af[mf], bfr[nf], acc[mf][nf], 0, 0, 0);
    aptr += 32;
    bptr += 32;
  }
  const int rowbase = blockIdx.x * 128 + wr * 64 + ((l >> 4) * 4);
  const int colbase = blockIdx.y * 128 + wc * 64 + (l & 15);
#pragma unroll
  for (int nf = 0; nf < 4; nf++) {
    int col = colbase + nf * 16;
    if (col >= N) continue;
    float bv = (EPI == 0) ? 0.f : bias[col];
#pragma unroll
    for (int mf = 0; mf < 4; mf++) {
#pragma unroll
      for (int i = 0; i < 4; i++) {
        long row = rowbase + mf * 16 + i;
        float v = acc[mf][nf][i] + bv;
        if (EPI == 2) v = gelu_exact(v);
        if (EPI == 1) {
          v += res[row * ldo + col];
          ((float*)outv)[row * ldo + col] = v;
        } else {
          ((u16*)outv)[row * ldo + col] = f2bf(v);
        }
      }
    }
  }
}

// ---------------- flash attention, 4-way KV split ----------------
// qkv [8192,192] bf16. Block = 128 threads (2 waves), 32 Q rows, 512 keys per split.
// Writes unnormalized partial O (f32) + per-row (m, l).
__global__ __launch_bounds__(128)
void attn_fwd(const u16* __restrict__ qkv, float* __restrict__ pout,
              float* __restrict__ pm, float* __restrict__ pl) {
  __shared__ __align__(16) u16 Klds[32 * 72];      // [key][feat] padded 64->72
  __shared__ __align__(16) u16 Vlds[64 * 40];      // [feat][key] padded 32->40
  __shared__ __align__(16) u16 Plds[2][16 * 40];   // per-wave P tile [qrow][key]
  const int t = threadIdx.x, w = t >> 6, l = t & 63;
  const int r0 = blockIdx.x * 32;
  const int sp = blockIdx.y;                        // KV split 0..3
  const long bb = (long)(r0 & ~2047);               // batch row base
  const int qrow = r0 + w * 16 + (l & 15);
  bf16x8 qf0 = *(const bf16x8*)(qkv + (long)qrow * 192 + ((l >> 4) * 8));
  bf16x8 qf1 = *(const bf16x8*)(qkv + (long)qrow * 192 + 32 + ((l >> 4) * 8));
  f32x4 po[4] = {};
  float m_i[4], l_i[4];
#pragma unroll
  for (int i = 0; i < 4; i++) { m_i[i] = -1e30f; l_i[i] = 0.f; }
  const int kkey = t >> 3, kseg = t & 7;
  for (int st = sp * 512; st < sp * 512 + 512; st += 32) {
    uint4 k0 = *(const uint4*)(qkv + (bb + st + kkey) * 192 + 64 + kseg * 8);
    uint4 k1 = *(const uint4*)(qkv + (bb + st + 16 + kkey) * 192 + 64 + kseg * 8);
    u16 vv[16];
#pragma unroll
    for (int i = 0; i < 16; i++) {
      int e = t + 128 * i;
      vv[i] = qkv[(bb + st + (e >> 6)) * 192 + 128 + (e & 63)];
    }
    __syncthreads();  // prior iter's LDS reads done
    *(uint4*)(&Klds[kkey * 72 + kseg * 8]) = k0;
    *(uint4*)(&Klds[(16 + kkey) * 72 + kseg * 8]) = k1;
#pragma unroll
    for (int i = 0; i < 16; i++) {
      int e = t + 128 * i;
      Vlds[(e & 63) * 40 + (e >> 6)] = vv[i];  // transposed store
    }
    __syncthreads();
    f32x4 s0 = {}, s1 = {};
    {
      bf16x8 ka = *(const bf16x8*)(&Klds[(l & 15) * 72 + ((l >> 4) * 8)]);
      bf16x8 kb = *(const bf16x8*)(&Klds[(l & 15) * 72 + 32 + ((l >> 4) * 8)]);
      s0 = __builtin_amdgcn_mfma_f32_16x16x32_bf16(qf0, ka, s0, 0, 0, 0);
      s0 = __builtin_amdgcn_mfma_f32_16x16x32_bf16(qf1, kb, s0, 0, 0, 0);
      bf16x8 kc = *(const bf16x8*)(&Klds[(16 + (l & 15)) * 72 + ((l >> 4) * 8)]);
      bf16x8 kd = *(const bf16x8*)(&Klds[(16 + (l & 15)) * 72 + 32 + ((l >> 4) * 8)]);
      s1 = __builtin_amdgcn_mfma_f32_16x16x32_bf16(qf0, kc, s1, 0, 0, 0);
      s1 = __builtin_amdgcn_mfma_f32_16x16x32_bf16(qf1, kd, s1, 0, 0, 0);
    }
    float sf[4];
#pragma unroll
    for (int i = 0; i < 4; i++) {
      float a = s0[i] * 0.125f, b = s1[i] * 0.125f;
      float tm = fmaxf(a, b);
#pragma unroll
      for (int off = 1; off < 16; off <<= 1) tm = fmaxf(tm, __shfl_xor(tm, off));
      float mn = fmaxf(m_i[i], tm);
      sf[i] = __expf(m_i[i] - mn);
      m_i[i] = mn;
      a = __expf(a - mn);
      b = __expf(b - mn);
      float rs = a + b;
#pragma unroll
      for (int off = 1; off < 16; off <<= 1) rs += __shfl_xor(rs, off);
      l_i[i] = l_i[i] * sf[i] + rs;
      int prow = (l >> 4) * 4 + i;
      Plds[w][prow * 40 + (l & 15)] = f2bf(a);
      Plds[w][prow * 40 + 16 + (l & 15)] = f2bf(b);
    }
#pragma unroll
    for (int n = 0; n < 4; n++)
#pragma unroll
      for (int i = 0; i < 4; i++) po[n][i] *= sf[i];
    bf16x8 pf = *(const bf16x8*)(&Plds[w][(l & 15) * 40 + ((l >> 4) * 8)]);
#pragma unroll
    for (int n = 0; n < 4; n++) {
      bf16x8 vf = *(const bf16x8*)(&Vlds[(n * 16 + (l & 15)) * 40 + ((l >> 4) * 8)]);
      po[n] = __builtin_amdgcn_mfma_f32_16x16x32_bf16(pf, vf, po[n], 0, 0, 0);
    }
  }
#pragma unroll
  for (int i = 0; i < 4; i++) {
    long row = r0 + w * 16 + ((l >> 4) * 4) + i;
    if ((l & 15) == 0) {
      pm[(long)sp * 8192 + row] = m_i[i];
      pl[(long)sp * 8192 + row] = l_i[i];
    }
#pragma unroll
    for (int n = 0; n < 4; n++)
      pout[((long)sp * 8192 + row) * 64 + n * 16 + (l & 15)] = po[n][i];
  }
}

// merge 4 KV-split partials -> normalized bf16 head output
__global__ __launch_bounds__(256)
void attn_merge(const float* __restrict__ pout, const float* __restrict__ pm,
                const float* __restrict__ pl, u16* __restrict__ oh) {
  int gid = blockIdx.x * 256 + threadIdx.x;  // row*64 + feat
  int row = gid >> 6;
  float M = -1e30f;
#pragma unroll
  for (int s = 0; s < 4; s++) M = fmaxf(M, pm[s * 8192 + row]);
  float L = 0.f, acc = 0.f;
#pragma unroll
  for (int s = 0; s < 4; s++) {
    float e = __expf(pm[s * 8192 + row] - M);
    L += pl[s * 8192 + row] * e;
    acc += pout[((long)s * 8192 + row) * 64 + (gid & 63)] * e;
  }
  oh[gid] = f2bf(acc / L);
}

extern "C" void kernel_launch(void* const* d_in, const int* in_sizes, int n_in,
                              void* d_out, int out_size, void* d_ws, size_t ws_size,
                              hipStream_t stream) {
  const float* x = (const float*)d_in[0];
  const float* wq = (const float*)d_in[1];
  const float* wk = (const float*)d_in[2];
  const float* wv = (const float*)d_in[3];
  const float* lin_w = (const float*)d_in[4];
  const float* lin_b = (const float*)d_in[5];
  const float* ln1_g = (const float*)d_in[6];
  const float* ln1_b = (const float*)d_in[7];
  const float* fc1_w = (const float*)d_in[8];
  const float* fc1_b = (const float*)d_in[9];
  const float* fc2_w = (const float*)d_in[10];
  const float* fc2_b = (const float*)d_in[11];
  float* out = (float*)d_out;

  char* p = (char*)d_ws;
  u16* wqkvT = (u16*)p; p += 256 * 768 * 2;          // [256(pad from 192), 768]
  u16* weffT = (u16*)p; p += 768 * 64 * 2;           // [768, 64]
  u16* fc1wT = (u16*)p; p += (size_t)3072 * 768 * 2; // [3072, 768]
  u16* fc2wT = (u16*)p; p += (size_t)768 * 3072 * 2; // [768, 3072]
  u16* h = (u16*)p; p += (size_t)8192 * 768 * 2;     // LN out (reused for LN2 out)
  u16* qkv = (u16*)p; p += (size_t)8192 * 192 * 2;   // [rows, q|k|v]
  u16* oh = (u16*)p; p += (size_t)8192 * 64 * 2;     // attention head out
  float* out1 = (float*)p; p += (size_t)8192 * 768 * 4;  // residual-1 output
  u16* a1 = (u16*)p; p += (size_t)8192 * 3072 * 2;   // gelu(fc1) out
  // attention partials alias a1 (a1 written only later, by FC1)
  float* pout = (float*)a1;                           // 4*8192*64 f32 = 8 MB
  float* pm = pout + (size_t)4 * 8192 * 64;
  float* pl = pm + 4 * 8192;

  dim3 tb(32, 8);
  // weight prep (bf16, transposed [N,K])
  transpose_cast<<<dim3(2, 24), tb, 0, stream>>>(wq, wqkvT, 768, 64);
  transpose_cast<<<dim3(2, 24), tb, 0, stream>>>(wk, wqkvT + 64 * 768, 768, 64);
  transpose_cast<<<dim3(2, 24), tb, 0, stream>>>(wv, wqkvT + 128 * 768, 768, 64);
  hipMemsetAsync(wqkvT + 192 * 768, 0, 64 * 768 * 2, stream);  // pad rows 192..255
  transpose_cast<<<dim3(96, 24), tb, 0, stream>>>(fc1_w, fc1wT, 768, 3072);
  transpose_cast<<<dim3(24, 96), tb, 0, stream>>>(fc2_w, fc2wT, 3072, 768);
  weff_build<<<192, 256, 0, stream>>>(lin_w, weffT);

  // pipeline
  ln_rows<<<2048, 256, 0, stream>>>(x, ln1_g, ln1_b, h, 8192);
  gemm_bt<0><<<dim3(64, 2), 256, 0, stream>>>(h, wqkvT, nullptr, nullptr, qkv,
                                              8192, 192, 768, 192);
  attn_fwd<<<dim3(256, 4), 128, 0, stream>>>(qkv, pout, pm, pl);
  attn_merge<<<2048, 256, 0, stream>>>(pout, pm, pl, oh);
  gemm_bt<1><<<dim3(64, 6), 256, 0, stream>>>(oh, weffT, lin_b, x, out1,
                                              8192, 768, 64, 768);
  ln_rows<<<2048, 256, 0, stream>>>(out1, ln1_g, ln1_b, h, 8192);
  gemm_bt<2><<<dim3(64, 24), 256, 0, stream>>>(h, fc1wT, fc1_b, nullptr, a1,
                                               8192, 3072, 768, 3072);
  gemm_bt<1><<<dim3(64, 6), 256, 0, stream>>>(a1, fc2wT, fc2_b, out1, out,
                                              8192, 768, 3072, 768);
}